// Round 9
// baseline (161.929 us; speedup 1.0000x reference)
//
#include <hip/hip_runtime.h>
#include <cstdint>
#include <cstddef>

#define G_ 8
#define T_ 2048
#define H_ 512
#define E_ 8
#define F_ 2048
#define C_ 256

typedef __bf16 bf16x8 __attribute__((ext_vector_type(8)));
typedef float f32x4 __attribute__((ext_vector_type(4)));

__device__ __forceinline__ unsigned short f2bf(float f) {
  unsigned u = __float_as_uint(f);
  u += 0x7FFFu + ((u >> 16) & 1u);
  return (unsigned short)(u >> 16);
}

__device__ __forceinline__ void gload_lds16(const void* g, void* l) {
  __builtin_amdgcn_global_load_lds(
      (const __attribute__((address_space(1))) void*)g,
      (__attribute__((address_space(3))) void*)l, 16, 0, 0);
}

// fast gelu (tanh form via sigmoid): gelu(v) = v * sigmoid(1.59577*v + 0.0713541*v^3)
__device__ __forceinline__ float fast_gelu(float v) {
  float z = v * (1.5957691216f + 0.0713540727f * v * v);
  float e = __expf(-z);
  return v * __builtin_amdgcn_rcpf(1.0f + e);
}

#define BARRIER() do { __builtin_amdgcn_s_barrier(); asm volatile("" ::: "memory"); } while (0)
#define WAIT_LDS() do { asm volatile("s_waitcnt lgkmcnt(0)" ::: "memory"); \
                        __builtin_amdgcn_sched_barrier(0); } while (0)

// ---------------- transpose + fp32->bf16 convert (64x64 tiles), body ----------------
__device__ __forceinline__ void transconv_body(const float* __restrict__ in,
                                               unsigned short* __restrict__ out,
                                               int R, int Cc, int tC, int bidrem,
                                               float* smem) {
  int tid = threadIdx.x;
  int nT = (R / 64) * tC;
  int b = bidrem / nT;
  int rem = bidrem % nT;
  int tr = rem / tC, tc = rem % tC;
  const float* ib = in + (size_t)b * R * Cc + (size_t)(tr * 64) * Cc + tc * 64;
  unsigned short* ob = out + (size_t)b * R * Cc;
  int lr = tid >> 4, lc = (tid & 15) * 4;
#pragma unroll
  for (int i = 0; i < 4; ++i) {
    float4 v = *(const float4*)&ib[(size_t)(lr + 16 * i) * Cc + lc];
    smem[(lr + 16 * i) * 65 + lc + 0] = v.x;
    smem[(lr + 16 * i) * 65 + lc + 1] = v.y;
    smem[(lr + 16 * i) * 65 + lc + 2] = v.z;
    smem[(lr + 16 * i) * 65 + lc + 3] = v.w;
  }
  __syncthreads();
  int r = (tid & 31) * 2, c0 = tid >> 5;
#pragma unroll
  for (int i = 0; i < 8; ++i) {
    int c = c0 + i * 8;
    ushort2 o;
    o.x = f2bf(smem[r * 65 + c]);
    o.y = f2bf(smem[(r + 1) * 65 + c]);
    *(ushort2*)&ob[(size_t)(tc * 64 + c) * R + tr * 64 + r] = o;
  }
}

// ---------------- router body: probs_et [G][E][T] fp32 ----------------
__device__ __forceinline__ void router_body(const float* __restrict__ x,
                                            const float* __restrict__ rk,
                                            const float* __restrict__ rb,
                                            float* __restrict__ probs,
                                            int bidrem, float* rks) {
  int tid = threadIdx.x;
  for (int i = tid; i < H_ * E_ / 4; i += 256)
    ((float4*)rks)[i] = ((const float4*)rk)[i];
  __syncthreads();
  int wid = tid >> 6, lane = tid & 63;
  int row = bidrem * 4 + wid;  // g*T + t
  float acc[E_];
#pragma unroll
  for (int e = 0; e < E_; ++e) acc[e] = 0.f;
  const float* xr = x + (size_t)row * H_;
#pragma unroll
  for (int j = 0; j < H_ / 64; ++j) {
    int h = j * 64 + lane;
    float xv = xr[h];
    const float4* r4 = (const float4*)&rks[h * E_];
    float4 r0 = r4[0], r1 = r4[1];
    acc[0] += xv * r0.x; acc[1] += xv * r0.y; acc[2] += xv * r0.z; acc[3] += xv * r0.w;
    acc[4] += xv * r1.x; acc[5] += xv * r1.y; acc[6] += xv * r1.z; acc[7] += xv * r1.w;
  }
#pragma unroll
  for (int e = 0; e < E_; ++e) {
#pragma unroll
    for (int off = 32; off > 0; off >>= 1) acc[e] += __shfl_xor(acc[e], off);
  }
  float l[E_];
  float mx = -1e30f;
#pragma unroll
  for (int e = 0; e < E_; ++e) { l[e] = acc[e] + rb[e]; mx = fmaxf(mx, l[e]); }
  float s = 0.f;
#pragma unroll
  for (int e = 0; e < E_; ++e) { l[e] = expf(l[e] - mx); s += l[e]; }
  float inv = 1.0f / s;
  int g = row >> 11, t = row & (T_ - 1);
  if (lane < E_) probs[((size_t)(g * E_ + lane)) * T_ + t] = l[lane] * inv;
}

// ---------------- fused1: wi-transpose | wo-transpose | router | cnt-zero ----------------
__global__ __launch_bounds__(256) void fused1_kernel(const float* __restrict__ wi,
                                                     unsigned short* __restrict__ wiT,
                                                     const float* __restrict__ wo,
                                                     unsigned short* __restrict__ woT,
                                                     const float* __restrict__ x,
                                                     const float* __restrict__ rk,
                                                     const float* __restrict__ rb,
                                                     float* __restrict__ probs,
                                                     int* __restrict__ cnt) {
  __shared__ float smem[64 * 65];  // 16.6KB; router uses first 4096 floats
  int bid = blockIdx.x;
  if (bid < 2048) {
    transconv_body(wi, wiT, H_, F_, F_ / 64, bid, smem);         // [E][H][F]->[E][F][H]
  } else if (bid < 4096) {
    transconv_body(wo, woT, F_, H_, H_ / 64, bid - 2048, smem);  // [E][F][H]->[E][H][F]
  } else if (bid < 8192) {
    router_body(x, rk, rb, probs, bid - 4096, smem);
  } else {
    // zero cnt[G][T]: 16 blocks x 256 thr x int4
    int id = (bid - 8192) * 256 + threadIdx.x;
    ((int4*)cnt)[id] = make_int4(0, 0, 0, 0);
  }
}

// ---------------- top-k (k=256) per (g,e) via bitonic sort + reverse-routing build ------
__global__ __launch_bounds__(1024) void topk_kernel(const float* __restrict__ probs,
                                                    int* __restrict__ idx,
                                                    float* __restrict__ gate,
                                                    int* __restrict__ cnt,
                                                    unsigned short* __restrict__ ent) {
  __shared__ unsigned long long keys[T_];  // 16KB
  int ge = blockIdx.x, tid = threadIdx.x;
  const float* p = probs + (size_t)ge * T_;
#pragma unroll
  for (int j = 0; j < 2; ++j) {
    int t = tid + j * 1024;
    unsigned pb = __float_as_uint(p[t]);  // softmax output > 0 -> bits monotonic
    keys[t] = ((unsigned long long)pb << 32) | (unsigned)(~t);  // tie: lower t wins
  }
  __syncthreads();
  for (unsigned k = 2; k <= T_; k <<= 1) {
    for (unsigned j = k >> 1; j > 0; j >>= 1) {
      unsigned w = tid;  // 1024 = T_/2 compare pairs
      unsigned i = ((w & ~(j - 1)) << 1) | (w & (j - 1));
      unsigned q = i + j;
      unsigned long long a = keys[i], b = keys[q];
      bool sw = ((i & k) == 0) ? (a < b) : (a > b);  // descending sort
      if (sw) { keys[i] = b; keys[q] = a; }
      __syncthreads();
    }
  }
  if (tid < C_) {
    unsigned long long kk = keys[tid];
    gate[ge * C_ + tid] = __uint_as_float((unsigned)(kk >> 32));
    int t = (int)(~(unsigned)kk);
    idx[ge * C_ + tid] = t;
    // reverse routing (cnt zeroed by fused1, which completed earlier on this stream)
    int g = ge >> 3, e = ge & 7;
    int pos = atomicAdd(&cnt[g * T_ + t], 1);  // pos < 8
    ent[(g * T_ + t) * 8 + pos] = (unsigned short)((e << 8) | tid);
  }
}

// ---------------- gather: xin[ge][c][h] bf16 = x[g][idx][h] ----------------
__global__ __launch_bounds__(256) void gather_kernel(const float* __restrict__ x,
                                                     const int* __restrict__ idx,
                                                     unsigned short* __restrict__ xin) {
  int tid = threadIdx.x, wid = tid >> 6, lane = tid & 63;
  int r = blockIdx.x * 4 + wid;  // ge*C + c
  int ge = r >> 8;
  int g = ge >> 3;
  int t = idx[r];
  const float* src = x + ((size_t)(g * T_ + t)) * H_;
  unsigned short* dst = xin + (size_t)r * H_;
#pragma unroll
  for (int j = 0; j < 2; ++j) {
    int h = j * 256 + lane * 4;
    float4 v = *(const float4*)&src[h];
    ushort4 o;
    o.x = f2bf(v.x); o.y = f2bf(v.y); o.z = f2bf(v.z); o.w = f2bf(v.w);
    *(ushort4*)&dst[h] = o;
  }
}

// ---------------- combine: y[g][t][h] = sum_i gate_i * eout[ge_i][c_i][h] ----------------
// Writes every y row (n==0 -> zeros), so no y memset is needed.
__global__ __launch_bounds__(256) void combine_kernel(const unsigned short* __restrict__ eout,
                                                      const int* __restrict__ cnt,
                                                      const unsigned short* __restrict__ ent,
                                                      const float* __restrict__ gate,
                                                      float* __restrict__ y) {
  int tid = threadIdx.x, wid = tid >> 6, lane = tid & 63;
  int row = blockIdx.x * 4 + wid;  // g*T + t
  int g = row >> 11;
  int n = cnt[row];
  float a[8] = {0.f, 0.f, 0.f, 0.f, 0.f, 0.f, 0.f, 0.f};
  for (int i = 0; i < n; ++i) {
    unsigned pe = ent[row * 8 + i];
    int e = pe >> 8, c = pe & 255;
    int ge = g * E_ + e;
    float gv = gate[ge * C_ + c];
    bf16x8 v = *(const bf16x8*)&eout[((size_t)ge * C_ + c) * H_ + lane * 8];
#pragma unroll
    for (int j = 0; j < 8; ++j) a[j] += gv * (float)v[j];
  }
  float* yr = y + (size_t)row * H_ + lane * 8;
  *(float4*)yr = make_float4(a[0], a[1], a[2], a[3]);
  *(float4*)(yr + 4) = make_float4(a[4], a[5], a[6], a[7]);
}

// ================== GEMM1 core: m201-faithful 8-phase, 256x256 tile, BK=64 ==================
// 8 waves (2M x 4N), wave tile 128x64. LDS 128KB = 2 dbuf x {A[2 khalf][256r x 32k],
// B[2 khalf][256r x 32k]}; half-tile = one khalf (16KB, 2 gload issues/thread).
// Pair-fused LDS rows (128B = two global 32k-rows), 16B blocks XOR-swizzled by (ldsrow&7):
// linear gload dest + inverse-permuted source + matching swizzled ds_read (0 conflicts).
// Per K-tile: 4 phases, each {ds_read frags | issue 1 half-tile of t+1 -> barrier ->
// lgkmcnt(0)+sched_barrier -> setprio -> 16 MFMA -> barrier}. vmcnt(4) only at P1/P3
// (never 0 in-loop): P3's covers next tile's kh0A/B, P1's covers this tile's kh1A/B.
template<int NT>  // NT = K/64
__device__ __forceinline__ void gemm_core256_8ph(const unsigned short* __restrict__ Abase,
                                                 const unsigned short* __restrict__ Bbase,
                                                 int ldK, unsigned short* lds,
                                                 f32x4 (&acc)[8][4]) {
  int tid = threadIdx.x;
  int wid = tid >> 6, lane = tid & 63;
  int l15 = lane & 15, g4 = lane >> 4;
  int wm = wid >> 2, wn = wid & 3;  // 2 x 4 waves

  auto mkoff = [&](int ob) {  // ob = byte offset within an 8192-elem (16KB) khalf region
    int lr = ob >> 7, b = ((ob >> 4) & 7) ^ (lr & 7);
    return (2 * lr + (b >> 2)) * ldK + (b & 3) * 8;
  };
  int off0 = mkoff(tid * 16);          // issue 0: LDS rows 0-63 (global rows 0-127)
  int off1 = mkoff(8192 + tid * 16);   // issue 1: LDS rows 64-127 (global rows 128-255)

  int blkphys = (((l15 & 1) << 2) | g4) ^ (l15 >> 1);
  int abase = wm * 4096 + (l15 >> 1) * 64 + blkphys * 8;           // + kk*8192 + m*512
  int bbase = 16384 + wn * 2048 + (l15 >> 1) * 64 + blkphys * 8;   // + kk*8192 + n*512

  // part: 0 = A-kh0, 1 = B-kh0, 2 = A-kh1, 3 = B-kh1  (of tile kt)
  auto stage = [&](int kt, int part) {
    unsigned short* sb = lds + (kt & 1) * 32768;
    const unsigned short* gsrc;
    unsigned short* dst;
    if (part == 0)      { gsrc = Abase + kt * 64;      dst = sb; }
    else if (part == 1) { gsrc = Bbase + kt * 64;      dst = sb + 16384; }
    else if (part == 2) { gsrc = Abase + kt * 64 + 32; dst = sb + 8192; }
    else                { gsrc = Bbase + kt * 64 + 32; dst = sb + 24576; }
    gload_lds16(gsrc + off0, dst + wid * 512);
    gload_lds16(gsrc + off1, dst + 4096 + wid * 512);
  };

  bf16x8 af[8], bA, bB;
  auto rdA = [&](const unsigned short* sb, int kk) {
#pragma unroll
    for (int m = 0; m < 8; ++m) af[m] = *(const bf16x8*)&sb[abase + kk * 8192 + m * 512];
  };
  auto rdB = [&](const unsigned short* sb, int kk, int q) {
    bA = *(const bf16x8*)&sb[bbase + kk * 8192 + (2 * q) * 512];
    bB = *(const bf16x8*)&sb[bbase + kk * 8192 + (2 * q + 1) * 512];
  };
  auto mma = [&](int q) {
    __builtin_amdgcn_s_setprio(1);
#pragma unroll
    for (int m = 0; m < 8; ++m) {
      acc[m][2 * q]     = __builtin_amdgcn_mfma_f32_16x16x32_bf16(af[m], bA, acc[m][2 * q], 0, 0, 0);
      acc[m][2 * q + 1] = __builtin_amdgcn_mfma_f32_16x16x32_bf16(af[m], bB, acc[m][2 * q + 1], 0, 0, 0);
    }
    __builtin_amdgcn_s_setprio(0);
  };

  // prologue: all 4 parts of tile 0; kh0A/B must be complete before P0
  stage(0, 0); stage(0, 1); stage(0, 2); stage(0, 3);
  asm volatile("s_waitcnt vmcnt(4)" ::: "memory");
  BARRIER();
  for (int kt = 0; kt < NT; ++kt) {
    const unsigned short* sb = lds + (kt & 1) * 32768;
    bool pf = (kt + 1 < NT);
    // ---- P0: kk=0, n-pair 0 ----
    rdA(sb, 0); rdB(sb, 0, 0);          // 10 ds_read_b128
    if (pf) stage(kt + 1, 0);
    BARRIER(); WAIT_LDS();
    mma(0);
    BARRIER();
    // ---- P1: kk=0, n-pair 1 ----
    rdB(sb, 0, 1);
    if (pf) stage(kt + 1, 1);
    if (pf) asm volatile("s_waitcnt vmcnt(4)" ::: "memory");   // this tile's kh1A/B landed
    else    asm volatile("s_waitcnt vmcnt(0)" ::: "memory");
    BARRIER(); WAIT_LDS();
    mma(1);
    BARRIER();
    // ---- P2: kk=1, n-pair 0 ----
    rdA(sb, 1); rdB(sb, 1, 0);
    if (pf) stage(kt + 1, 2);
    BARRIER(); WAIT_LDS();
    mma(0);
    BARRIER();
    // ---- P3: kk=1, n-pair 1 ----
    rdB(sb, 1, 1);
    if (pf) stage(kt + 1, 3);
    if (pf) asm volatile("s_waitcnt vmcnt(4)" ::: "memory");   // next tile's kh0A/B landed
    BARRIER(); WAIT_LDS();
    mma(1);
    BARRIER();
  }
}

// ---------------- GEMM1: hmid = gelu(xin @ wi + bi), bf16 out ----------------
// grid 512 = 8e * 8nt * 8g; expert->XCD swizzle; 512 thr, 128KB LDS (1 block/CU).
__global__ __launch_bounds__(512, 2) void gemm1_kernel(const unsigned short* __restrict__ xin,
                                                       const unsigned short* __restrict__ wiT,
                                                       const float* __restrict__ bi,
                                                       unsigned short* __restrict__ hmid) {
  __shared__ unsigned short lds[65536];  // 128KB
  int bid = blockIdx.x;
  int swz = (bid & 7) * 64 + (bid >> 3);  // bijective, 512 % 8 == 0; e == XCD
  int e = swz >> 6, rem = swz & 63, nt = rem >> 3, g = rem & 7;
  int ge = g * E_ + e;
  const unsigned short* Abase = xin + (size_t)ge * C_ * H_;
  const unsigned short* Bbase = wiT + (size_t)e * F_ * H_ + (size_t)(nt * 256) * H_;
  f32x4 acc[8][4] = {};
  gemm_core256_8ph<H_ / 64>(Abase, Bbase, H_, lds, acc);

  int tid = threadIdx.x, wid = tid >> 6, lane = tid & 63;
  int l15 = lane & 15, g4 = lane >> 4, wm = wid >> 2, wn = wid & 3;
  unsigned short* Cb = hmid + (size_t)ge * C_ * F_;
  int row0 = wm * 128, col0 = nt * 256 + wn * 64;
#pragma unroll
  for (int m = 0; m < 8; ++m) {
#pragma unroll
    for (int n = 0; n < 4; ++n) {
      int col = col0 + n * 16 + l15;
      float bv = bi[e * F_ + col];
#pragma unroll
      for (int r = 0; r < 4; ++r) {
        int row = row0 + m * 16 + g4 * 4 + r;
        Cb[(size_t)row * F_ + col] = f2bf(fast_gelu(acc[m][n][r] + bv));
      }
    }
  }
}

// ================== GEMM2 core: 128x128 tile, BK=32, 4-slot ring, 256 thr (r8) =============
template<int NT>
__device__ __forceinline__ void gemm_core128(const unsigned short* __restrict__ Abase,
                                             const unsigned short* __restrict__ Bbase,
                                             int ldK, unsigned short* lds,
                                             f32x4 (&acc)[4][4]) {
  int tid = threadIdx.x;
  int wid = tid >> 6, lane = tid & 63;
  int l15 = lane & 15, g4 = lane >> 4;
  int wm = wid >> 1, wn = wid & 1;  // 2x2 waves, wave-tile 64x64

  auto mkoff = [&](int ob) {
    int lr = ob >> 7, b = ((ob >> 4) & 7) ^ (lr & 7);
    return (2 * lr + (b >> 2)) * ldK + (b & 3) * 8;
  };
  int off0 = mkoff(tid * 16);          // bytes [0,4096) of a 4096-elem region
  int off1 = mkoff(4096 + tid * 16);   // bytes [4096,8192)

  int blkphys = (((l15 & 1) << 2) | g4) ^ (l15 >> 1);
  int abase = (wm * 32 + (l15 >> 1)) * 64 + blkphys * 8;          // + m*512
  int bbase = 4096 + (wn * 32 + (l15 >> 1)) * 64 + blkphys * 8;   // + n*512

  auto stage = [&](int kt) {
    unsigned short* sb = lds + (kt & 3) * 8192;  // 16KB slots
    const unsigned short* ga = Abase + kt * 32;
    const unsigned short* gb = Bbase + kt * 32;
    gload_lds16(ga + off0, sb + wid * 512);
    gload_lds16(ga + off1, sb + 2048 + wid * 512);
    gload_lds16(gb + off0, sb + 4096 + wid * 512);
    gload_lds16(gb + off1, sb + 6144 + wid * 512);
  };

  auto compute = [&](int kt) {
    const unsigned short* sb = lds + (kt & 3) * 8192;
    bf16x8 af[4], bfr[4];
#pragma unroll
    for (int m = 0; m < 4; ++m) af[m] = *(const bf16x8*)&sb[abase + m * 512];
#pragma unroll
    for (int n = 0; n < 4; ++n) bfr[n] = *(const bf16x8*)&sb[bbase + n * 512];
    __builtin_amdgcn_s_setprio(1);
#pragma unroll
    for (int m = 0; m < 4; ++m)
#pragma unroll
      for (int n = 0; n < 4; ++n)
        acc[m][n] = __builtin_amdgcn_mfma_f32_16x16x32_bf16(af[m], bfr[n], acc[m][n], 0, 0, 0);
    __builtin_amdgcn_s_setprio(0);
  };

  stage(0); stage(1); stage(2);
  asm volatile("s_waitcnt vmcnt(8)" ::: "memory");
  BARRIER();
  for (int kt = 0; kt < NT - 3; ++kt) {
    stage(kt + 3);
    compute(kt);
    asm volatile("s_waitcnt vmcnt(8)" ::: "memory");
    BARRIER();
  }
  compute(NT - 3);
  asm volatile("s_waitcnt vmcnt(4)" ::: "memory");
  BARRIER();
  compute(NT - 2);
  asm volatile("s_waitcnt vmcnt(0)" ::: "memory");
  BARRIER();
  compute(NT - 1);
}

// ---------------- GEMM2: eout[ge][c][h] = hmid @ wo + bo (bf16, no atomics) ----------------
// grid 512 = 8e * (2tm * 4tn * 8g); 2 blocks/CU.
__global__ __launch_bounds__(256, 2) void gemm2_kernel(const unsigned short* __restrict__ hmid,
                                                       const unsigned short* __restrict__ woT,
                                                       const float* __restrict__ bo,
                                                       unsigned short* __restrict__ eout) {
  __shared__ unsigned short lds[32768];  // 64KB
  int bid = blockIdx.x;
  int swz = (bid & 7) * 64 + (bid >> 3);  // bijective, 512 % 8 == 0
  int e = swz >> 6, rem = swz & 63;
  int tile = rem >> 3, g = rem & 7;       // tile: tm(2) x tn(4)
  int tm = tile >> 2, tn = tile & 3;
  int ge = g * E_ + e;
  const unsigned short* Abase = hmid + (size_t)ge * C_ * F_ + (size_t)(tm * 128) * F_;
  const unsigned short* Bbase = woT + (size_t)e * H_ * F_ + (size_t)(tn * 128) * F_;
  f32x4 acc[4][4] = {};
  gemm_core128<F_ / 32>(Abase, Bbase, F_, lds, acc);

  int tid = threadIdx.x, wid = tid >> 6, lane = tid & 63;
  int l15 = lane & 15, g4 = lane >> 4, wm = wid >> 1, wn = wid & 1;
  unsigned short* Ob = eout + (size_t)ge * C_ * H_;
  int row0 = tm * 128 + wm * 64, col0 = tn * 128 + wn * 64;
#pragma unroll
  for (int m = 0; m < 4; ++m) {
#pragma unroll
    for (int n = 0; n < 4; ++n) {
      int col = col0 + n * 16 + l15;
      float bv = bo[e * H_ + col];
#pragma unroll
      for (int r = 0; r < 4; ++r) {
        int row = row0 + m * 16 + g4 * 4 + r;
        Ob[(size_t)row * H_ + col] = f2bf(acc[m][n][r] + bv);
      }
    }
  }
}

extern "C" void kernel_launch(void* const* d_in, const int* in_sizes, int n_in,
                              void* d_out, int out_size, void* d_ws, size_t ws_size,
                              hipStream_t stream) {
  const float* x  = (const float*)d_in[0];
  const float* rk = (const float*)d_in[1];
  const float* rb = (const float*)d_in[2];
  const float* wi = (const float*)d_in[3];
  const float* bi = (const float*)d_in[4];
  const float* wo = (const float*)d_in[5];
  const float* bo = (const float*)d_in[6];
  float* y = (float*)d_out;

  // workspace layout (bytes) — eout overlays dead xin.
  const size_t WI_T = 0;                       // 16 MB bf16 [E][F][H]
  const size_t WO_T = 16777216;                // 16 MB bf16 [E][H][F]
  const size_t PROB = 33554432;                // 512 KB fp32 [G][E][T]
  const size_t CNTO = 34078720;                // 64 KB int32 [G][T]
  const size_t ENTO = 34144256;                // 256 KB u16 [G][T][8]
  const size_t IDXO = 34406400;                // 64 KB int32 [G][E][C]
  const size_t GATO = 34471936;                // 64 KB fp32
  const size_t XINO = 34537472;                // 16 MB bf16 [G][E][C][H] (later: eout)
  const size_t HMID = 51314688;                // 64 MB bf16 [G][E][C][F]
  const size_t NEED = 118423552;
  if (ws_size < NEED) return;  // insufficient scratch -> clean fail

  char* ws = (char*)d_ws;
  unsigned short* wiT = (unsigned short*)(ws + WI_T);
  unsigned short* woT = (unsigned short*)(ws + WO_T);
  float* probs = (float*)(ws + PROB);
  int* cnt = (int*)(ws + CNTO);
  unsigned short* ent = (unsigned short*)(ws + ENTO);
  int* idx = (int*)(ws + IDXO);
  float* gate = (float*)(ws + GATO);
  unsigned short* xin = (unsigned short*)(ws + XINO);
  unsigned short* eout = (unsigned short*)(ws + XINO);         // aliases xin (dead after gemm1)
  unsigned short* hmid = (unsigned short*)(ws + HMID);

  // transposes + router + cnt-zero fused (independent)
  fused1_kernel<<<8192 + 16, 256, 0, stream>>>(wi, wiT, wo, woT, x, rk, rb, probs, cnt);
  topk_kernel<<<G_ * E_, 1024, 0, stream>>>(probs, idx, gate, cnt, ent);
  gather_kernel<<<G_ * E_ * C_ / 4, 256, 0, stream>>>(x, idx, xin);
  gemm1_kernel<<<512, 512, 0, stream>>>(xin, wiT, bi, hmid);
  gemm2_kernel<<<512, 256, 0, stream>>>(hmid, woT, bo, eout);
  combine_kernel<<<G_ * T_ / 4, 256, 0, stream>>>(eout, cnt, ent, gate, y);
  // no y memset: combine writes every row unconditionally
}

// Round 10
// 143.942 us; speedup vs baseline: 1.1250x; 1.1250x over previous
//
#include <hip/hip_runtime.h>
#include <cstdint>
#include <cstddef>

#define G_ 8
#define T_ 2048
#define H_ 512
#define E_ 8
#define F_ 2048
#define C_ 256

typedef __bf16 bf16x8 __attribute__((ext_vector_type(8)));
typedef float f32x4 __attribute__((ext_vector_type(4)));

__device__ __forceinline__ unsigned short f2bf(float f) {
  unsigned u = __float_as_uint(f);
  u += 0x7FFFu + ((u >> 16) & 1u);
  return (unsigned short)(u >> 16);
}

__device__ __forceinline__ void gload_lds16(const void* g, void* l) {
  __builtin_amdgcn_global_load_lds(
      (const __attribute__((address_space(1))) void*)g,
      (__attribute__((address_space(3))) void*)l, 16, 0, 0);
}

// fast gelu (tanh form via sigmoid): gelu(v) = v * sigmoid(1.59577*v + 0.0713541*v^3)
__device__ __forceinline__ float fast_gelu(float v) {
  float z = v * (1.5957691216f + 0.0713540727f * v * v);
  float e = __expf(-z);
  return v * __builtin_amdgcn_rcpf(1.0f + e);
}

// ---------------- router (4096 blocks) + cnt-zero (16 blocks), 256 thr ----------------
__global__ __launch_bounds__(256) void router_kernel(const float* __restrict__ x,
                                                     const float* __restrict__ rk,
                                                     const float* __restrict__ rb,
                                                     float* __restrict__ probs,
                                                     int* __restrict__ cnt) {
  __shared__ float rks[H_ * E_];  // 16KB
  int bid = blockIdx.x, tid = threadIdx.x;
  if (bid >= 4096) {
    int id = (bid - 4096) * 256 + tid;
    ((int4*)cnt)[id] = make_int4(0, 0, 0, 0);
    return;
  }
  for (int i = tid; i < H_ * E_ / 4; i += 256)
    ((float4*)rks)[i] = ((const float4*)rk)[i];
  __syncthreads();
  int wid = tid >> 6, lane = tid & 63;
  int row = bid * 4 + wid;  // g*T + t
  float acc[E_];
#pragma unroll
  for (int e = 0; e < E_; ++e) acc[e] = 0.f;
  const float* xr = x + (size_t)row * H_;
#pragma unroll
  for (int j = 0; j < H_ / 64; ++j) {
    int h = j * 64 + lane;
    float xv = xr[h];
    const float4* r4 = (const float4*)&rks[h * E_];
    float4 r0 = r4[0], r1 = r4[1];
    acc[0] += xv * r0.x; acc[1] += xv * r0.y; acc[2] += xv * r0.z; acc[3] += xv * r0.w;
    acc[4] += xv * r1.x; acc[5] += xv * r1.y; acc[6] += xv * r1.z; acc[7] += xv * r1.w;
  }
#pragma unroll
  for (int e = 0; e < E_; ++e) {
#pragma unroll
    for (int off = 32; off > 0; off >>= 1) acc[e] += __shfl_xor(acc[e], off);
  }
  float l[E_];
  float mx = -1e30f;
#pragma unroll
  for (int e = 0; e < E_; ++e) { l[e] = acc[e] + rb[e]; mx = fmaxf(mx, l[e]); }
  float s = 0.f;
#pragma unroll
  for (int e = 0; e < E_; ++e) { l[e] = expf(l[e] - mx); s += l[e]; }
  float inv = 1.0f / s;
  int g = row >> 11, t = row & (T_ - 1);
  if (lane < E_) probs[((size_t)(g * E_ + lane)) * T_ + t] = l[lane] * inv;
}

// ---------------- transpose 64x64 tile with 1024 threads ----------------
__device__ __forceinline__ void transconv_1k(const float* __restrict__ in,
                                             unsigned short* __restrict__ out,
                                             int R, int Cc, int tC, int bidrem,
                                             float* smem) {
  int tid = threadIdx.x;
  int nT = (R / 64) * tC;
  int b = bidrem / nT;
  int rem = bidrem % nT;
  int tr = rem / tC, tc = rem % tC;
  const float* ib = in + (size_t)b * R * Cc + (size_t)(tr * 64) * Cc + tc * 64;
  unsigned short* ob = out + (size_t)b * R * Cc;
  int lr = tid >> 4, lc = (tid & 15) * 4;  // 64 rows x 16 thr x float4
  float4 v = *(const float4*)&ib[(size_t)lr * Cc + lc];
  smem[lr * 65 + lc + 0] = v.x;
  smem[lr * 65 + lc + 1] = v.y;
  smem[lr * 65 + lc + 2] = v.z;
  smem[lr * 65 + lc + 3] = v.w;
  __syncthreads();
  int c = tid >> 4;            // 64 out-rows (c)
  int r0 = (tid & 15) * 4;     // 4 consecutive r per thread -> ushort4
  ushort4 o;
  o.x = f2bf(smem[(r0 + 0) * 65 + c]);
  o.y = f2bf(smem[(r0 + 1) * 65 + c]);
  o.z = f2bf(smem[(r0 + 2) * 65 + c]);
  o.w = f2bf(smem[(r0 + 3) * 65 + c]);
  *(ushort4*)&ob[(size_t)(tc * 64 + c) * R + tr * 64 + r0] = o;
}

// ---------------- fused: topk (64) | wi-transpose (2048) | wo-transpose (2048) ----------
// topk blocks first so they start immediately; transposes are independent of topk.
__global__ __launch_bounds__(1024) void fused_tt_kernel(const float* __restrict__ probs,
                                                        int* __restrict__ idx,
                                                        float* __restrict__ gate,
                                                        int* __restrict__ cnt,
                                                        unsigned short* __restrict__ ent,
                                                        const float* __restrict__ wi,
                                                        unsigned short* __restrict__ wiT,
                                                        const float* __restrict__ wo,
                                                        unsigned short* __restrict__ woT) {
  __shared__ __align__(16) char shbuf[64 * 65 * 4];  // 16.6KB; topk uses 16KB as keys
  int bid = blockIdx.x, tid = threadIdx.x;
  if (bid >= 64) {
    float* smem = (float*)shbuf;
    int rem = bid - 64;
    if (rem < 2048) transconv_1k(wi, wiT, H_, F_, F_ / 64, rem, smem);          // [E][H][F]->[E][F][H]
    else            transconv_1k(wo, woT, F_, H_, H_ / 64, rem - 2048, smem);   // [E][F][H]->[E][H][F]
    return;
  }
  // ---- top-k (k=256) per (g,e) via bitonic sort + reverse-routing build ----
  unsigned long long* keys = (unsigned long long*)shbuf;  // 16KB
  int ge = bid;
  const float* p = probs + (size_t)ge * T_;
#pragma unroll
  for (int j = 0; j < 2; ++j) {
    int t = tid + j * 1024;
    unsigned pb = __float_as_uint(p[t]);  // softmax output > 0 -> bits monotonic
    keys[t] = ((unsigned long long)pb << 32) | (unsigned)(~t);  // tie: lower t wins
  }
  __syncthreads();
  for (unsigned k = 2; k <= T_; k <<= 1) {
    for (unsigned j = k >> 1; j > 0; j >>= 1) {
      unsigned w = tid;  // 1024 = T_/2 compare pairs
      unsigned i = ((w & ~(j - 1)) << 1) | (w & (j - 1));
      unsigned q = i + j;
      unsigned long long a = keys[i], b = keys[q];
      bool sw = ((i & k) == 0) ? (a < b) : (a > b);  // descending sort
      if (sw) { keys[i] = b; keys[q] = a; }
      __syncthreads();
    }
  }
  if (tid < C_) {
    unsigned long long kk = keys[tid];
    gate[ge * C_ + tid] = __uint_as_float((unsigned)(kk >> 32));
    int t = (int)(~(unsigned)kk);
    idx[ge * C_ + tid] = t;
    int g = ge >> 3, e = ge & 7;
    int pos = atomicAdd(&cnt[g * T_ + t], 1);  // pos < 8 (cnt zeroed in router launch)
    ent[(g * T_ + t) * 8 + pos] = (unsigned short)((e << 8) | tid);
  }
}

// ---------------- gather: xin[ge][c][h] bf16 = x[g][idx][h] ----------------
__global__ __launch_bounds__(256) void gather_kernel(const float* __restrict__ x,
                                                     const int* __restrict__ idx,
                                                     unsigned short* __restrict__ xin) {
  int tid = threadIdx.x, wid = tid >> 6, lane = tid & 63;
  int r = blockIdx.x * 4 + wid;  // ge*C + c
  int ge = r >> 8;
  int g = ge >> 3;
  int t = idx[r];
  const float* src = x + ((size_t)(g * T_ + t)) * H_;
  unsigned short* dst = xin + (size_t)r * H_;
#pragma unroll
  for (int j = 0; j < 2; ++j) {
    int h = j * 256 + lane * 4;
    float4 v = *(const float4*)&src[h];
    ushort4 o;
    o.x = f2bf(v.x); o.y = f2bf(v.y); o.z = f2bf(v.z); o.w = f2bf(v.w);
    *(ushort4*)&dst[h] = o;
  }
}

// ---------------- combine: y[g][t][h] = sum_i gate_i * eout[ge_i][c_i][h] ----------------
// Writes every y row (n==0 -> zeros), so no y memset is needed.
__global__ __launch_bounds__(256) void combine_kernel(const unsigned short* __restrict__ eout,
                                                      const int* __restrict__ cnt,
                                                      const unsigned short* __restrict__ ent,
                                                      const float* __restrict__ gate,
                                                      float* __restrict__ y) {
  int tid = threadIdx.x, wid = tid >> 6, lane = tid & 63;
  int row = blockIdx.x * 4 + wid;  // g*T + t
  int g = row >> 11;
  int n = cnt[row];
  float a[8] = {0.f, 0.f, 0.f, 0.f, 0.f, 0.f, 0.f, 0.f};
  for (int i = 0; i < n; ++i) {
    unsigned pe = ent[row * 8 + i];
    int e = pe >> 8, c = pe & 255;
    int ge = g * E_ + e;
    float gv = gate[ge * C_ + c];
    bf16x8 v = *(const bf16x8*)&eout[((size_t)ge * C_ + c) * H_ + lane * 8];
#pragma unroll
    for (int j = 0; j < 8; ++j) a[j] += gv * (float)v[j];
  }
  float* yr = y + (size_t)row * H_ + lane * 8;
  *(float4*)yr = make_float4(a[0], a[1], a[2], a[3]);
  *(float4*)(yr + 4) = make_float4(a[4], a[5], a[6], a[7]);
}

// ================== m97-style GEMM core: 128x128 tile, BK=64, 32KB single buffer ==========
// 256 thr (4 waves, 2x2 wave-tiles of 64x64). LDS: A[128 r][64 k] @0, B[128 r][64 k] @8192
// elems = 32KB -> ~4 blocks/CU co-resident; cross-block wave overlap (m114) hides the
// __syncthreads drains (m97 mechanism: 874 TF with this exact shape at N=4096).
// XOR swizzle both-sides: LDS(row, blk) holds global(row, blk^(row&7)); staged via
// linear-dest global_load_lds + inverse-permuted per-lane source; ds_read applies the
// same XOR -> 16-lane fragment reads spread 2-way over all 32 banks (free; 0 conflicts,
// validated r3-r9).
template<int NT>  // NT = K/64
__device__ __forceinline__ void gemm_core_m97(const unsigned short* __restrict__ Abase,
                                              const unsigned short* __restrict__ Bbase,
                                              int ldK, unsigned short* lds,
                                              f32x4 (&acc)[4][4]) {
  int tid = threadIdx.x;
  int wid = tid >> 6, lane = tid & 63;
  int l15 = lane & 15, g4 = lane >> 4;
  int wm = wid >> 1, wn = wid & 1;
  int swz = l15 & 7;

  // staging source offsets (elements): issue j covers LDS bytes [j*4096 + tid*16)
  int srcoff[4];
#pragma unroll
  for (int j = 0; j < 4; ++j) {
    int ob = j * 4096 + tid * 16;
    int lr = ob >> 7;                        // LDS row 0..127
    int blk = ((ob >> 4) & 7) ^ (lr & 7);    // inverse-permuted global 16B block
    srcoff[j] = lr * ldK + blk * 8;
  }

  for (int kt = 0; kt < NT; ++kt) {
    const unsigned short* ga = Abase + kt * 64;
    const unsigned short* gb = Bbase + kt * 64;
#pragma unroll
    for (int j = 0; j < 4; ++j) {
      gload_lds16(ga + srcoff[j], lds + j * 2048 + wid * 512);
      gload_lds16(gb + srcoff[j], lds + 8192 + j * 2048 + wid * 512);
    }
    __syncthreads();  // drains vmcnt: staged tile visible; co-resident blocks cover the stall
#pragma unroll
    for (int kk = 0; kk < 2; ++kk) {
      int cb = ((kk * 4 + g4) ^ swz) * 8;
      bf16x8 af[4], bf[4];
#pragma unroll
      for (int m = 0; m < 4; ++m)
        af[m] = *(const bf16x8*)&lds[(wm * 64 + m * 16 + l15) * 64 + cb];
#pragma unroll
      for (int n = 0; n < 4; ++n)
        bf[n] = *(const bf16x8*)&lds[8192 + (wn * 64 + n * 16 + l15) * 64 + cb];
      __builtin_amdgcn_s_setprio(1);
#pragma unroll
      for (int m = 0; m < 4; ++m)
#pragma unroll
        for (int n = 0; n < 4; ++n)
          acc[m][n] = __builtin_amdgcn_mfma_f32_16x16x32_bf16(af[m], bf[n], acc[m][n], 0, 0, 0);
      __builtin_amdgcn_s_setprio(0);
    }
    __syncthreads();
  }
}

// ---------------- GEMM1: hmid = gelu(xin @ wi + bi), bf16 out ----------------
// grid 2048 = 8e * (2tm * 16tn * 8g); e==XCD swizzle; 32KB LDS -> ~4 blocks/CU.
__global__ __launch_bounds__(256, 4) void gemm1_kernel(const unsigned short* __restrict__ xin,
                                                       const unsigned short* __restrict__ wiT,
                                                       const float* __restrict__ bi,
                                                       unsigned short* __restrict__ hmid) {
  __shared__ unsigned short lds[16384];  // 32KB
  int bid = blockIdx.x;
  int id = (bid & 7) * 256 + (bid >> 3);  // bijective, 2048 % 8 == 0; e == XCD
  int e = id >> 8, rem = id & 255;
  int tm = rem >> 7, tn = (rem >> 3) & 15, g = rem & 7;
  int ge = g * E_ + e;
  const unsigned short* Abase = xin + (size_t)ge * C_ * H_ + (size_t)(tm * 128) * H_;
  const unsigned short* Bbase = wiT + (size_t)e * F_ * H_ + (size_t)(tn * 128) * H_;
  f32x4 acc[4][4] = {};
  gemm_core_m97<H_ / 64>(Abase, Bbase, H_, lds, acc);

  int tid = threadIdx.x, wid = tid >> 6, lane = tid & 63;
  int l15 = lane & 15, g4 = lane >> 4, wm = wid >> 1, wn = wid & 1;
  unsigned short* Cb = hmid + (size_t)ge * C_ * F_;
  int row0 = tm * 128 + wm * 64, col0 = tn * 128 + wn * 64;
#pragma unroll
  for (int m = 0; m < 4; ++m) {
#pragma unroll
    for (int n = 0; n < 4; ++n) {
      int col = col0 + n * 16 + l15;
      float bv = bi[e * F_ + col];
#pragma unroll
      for (int r = 0; r < 4; ++r) {
        int row = row0 + m * 16 + g4 * 4 + r;
        Cb[(size_t)row * F_ + col] = f2bf(fast_gelu(acc[m][n][r] + bv));
      }
    }
  }
}

// ---------------- GEMM2: eout[ge][c][h] = hmid @ wo + bo (bf16, no atomics) ----------------
// grid 512 = 8e * (2tm * 4tn * 8g); 32KB LDS -> co-resident blocks.
__global__ __launch_bounds__(256, 4) void gemm2_kernel(const unsigned short* __restrict__ hmid,
                                                       const unsigned short* __restrict__ woT,
                                                       const float* __restrict__ bo,
                                                       unsigned short* __restrict__ eout) {
  __shared__ unsigned short lds[16384];  // 32KB
  int bid = blockIdx.x;
  int swz = (bid & 7) * 64 + (bid >> 3);  // bijective, 512 % 8 == 0
  int e = swz >> 6, rem = swz & 63;
  int tile = rem >> 3, g = rem & 7;       // tile: tm(2) x tn(4)
  int tm = tile >> 2, tn = tile & 3;
  int ge = g * E_ + e;
  const unsigned short* Abase = hmid + (size_t)ge * C_ * F_ + (size_t)(tm * 128) * F_;
  const unsigned short* Bbase = woT + (size_t)e * H_ * F_ + (size_t)(tn * 128) * F_;
  f32x4 acc[4][4] = {};
  gemm_core_m97<F_ / 64>(Abase, Bbase, F_, lds, acc);

  int tid = threadIdx.x, wid = tid >> 6, lane = tid & 63;
  int l15 = lane & 15, g4 = lane >> 4, wm = wid >> 1, wn = wid & 1;
  unsigned short* Ob = eout + (size_t)ge * C_ * H_;
  int row0 = tm * 128 + wm * 64, col0 = tn * 128 + wn * 64;
#pragma unroll
  for (int m = 0; m < 4; ++m) {
#pragma unroll
    for (int n = 0; n < 4; ++n) {
      int col = col0 + n * 16 + l15;
      float bv = bo[e * H_ + col];
#pragma unroll
      for (int r = 0; r < 4; ++r) {
        int row = row0 + m * 16 + g4 * 4 + r;
        Ob[(size_t)row * H_ + col] = f2bf(acc[m][n][r] + bv);
      }
    }
  }
}

extern "C" void kernel_launch(void* const* d_in, const int* in_sizes, int n_in,
                              void* d_out, int out_size, void* d_ws, size_t ws_size,
                              hipStream_t stream) {
  const float* x  = (const float*)d_in[0];
  const float* rk = (const float*)d_in[1];
  const float* rb = (const float*)d_in[2];
  const float* wi = (const float*)d_in[3];
  const float* bi = (const float*)d_in[4];
  const float* wo = (const float*)d_in[5];
  const float* bo = (const float*)d_in[6];
  float* y = (float*)d_out;

  // workspace layout (bytes) — eout overlays dead xin.
  const size_t WI_T = 0;                       // 16 MB bf16 [E][F][H]
  const size_t WO_T = 16777216;                // 16 MB bf16 [E][H][F]
  const size_t PROB = 33554432;                // 512 KB fp32 [G][E][T]
  const size_t CNTO = 34078720;                // 64 KB int32 [G][T]
  const size_t ENTO = 34144256;                // 256 KB u16 [G][T][8]
  const size_t IDXO = 34406400;                // 64 KB int32 [G][E][C]
  const size_t GATO = 34471936;                // 64 KB fp32
  const size_t XINO = 34537472;                // 16 MB bf16 [G][E][C][H] (later: eout)
  const size_t HMID = 51314688;                // 64 MB bf16 [G][E][C][F]
  const size_t NEED = 118423552;
  if (ws_size < NEED) return;  // insufficient scratch -> clean fail

  char* ws = (char*)d_ws;
  unsigned short* wiT = (unsigned short*)(ws + WI_T);
  unsigned short* woT = (unsigned short*)(ws + WO_T);
  float* probs = (float*)(ws + PROB);
  int* cnt = (int*)(ws + CNTO);
  unsigned short* ent = (unsigned short*)(ws + ENTO);
  int* idx = (int*)(ws + IDXO);
  float* gate = (float*)(ws + GATO);
  unsigned short* xin = (unsigned short*)(ws + XINO);
  unsigned short* eout = (unsigned short*)(ws + XINO);         // aliases xin (dead after gemm1)
  unsigned short* hmid = (unsigned short*)(ws + HMID);

  router_kernel<<<4096 + 16, 256, 0, stream>>>(x, rk, rb, probs, cnt);
  fused_tt_kernel<<<64 + 4096, 1024, 0, stream>>>(probs, idx, gate, cnt, ent,
                                                  wi, wiT, wo, woT);
  gather_kernel<<<G_ * E_ * C_ / 4, 256, 0, stream>>>(x, idx, xin);
  gemm1_kernel<<<2048, 256, 0, stream>>>(xin, wiT, bi, hmid);
  gemm2_kernel<<<512, 256, 0, stream>>>(hmid, woT, bo, eout);
  combine_kernel<<<G_ * T_ / 4, 256, 0, stream>>>(eout, cnt, ent, gate, y);
  // no y memset: combine writes every row unconditionally
}